// Round 6
// baseline (461.189 us; speedup 1.0000x reference)
//
#include <hip/hip_runtime.h>

// ---------------------------------------------------------------------------
// Fused equivariant FFN, bf16 MFMA (16x16x32), fp32 accumulate.
// Round 6: mm-dimension row-batched. x1 phases = ONE 96x192 GEMM + ONE 96x64
// GEMM (rows = mm*32+node); x2 = 160x96 + 160x32. Barriers 19 -> 7, all 8
// waves balanced in every phase. GEMM2 tile assignment keeps all mm of a
// (node,j) in one lane -> dense 12B/20B stores (no write amplification).
// LDS 71.2 KB -> 2 blocks/CU.
// ---------------------------------------------------------------------------

typedef __attribute__((ext_vector_type(8))) short short8;   // 8 bf16 = 4 VGPRs
typedef __attribute__((ext_vector_type(4))) float f32x4;

#define INV_M0f 0.08838834764831845f   // 1/sqrt(128)
#define INV_M1f 0.125f                 // 1/sqrt(64)
#define INV_M2f 0.17677669529663687f   // 1/sqrt(32)
#define INV_H0f 0.05103103630798288f   // 1/sqrt(384)
#define INV_H1f 0.07216878364870323f   // 1/sqrt(192)
#define INV_H2f 0.10206207261596577f   // 1/sqrt(96)

// packed bf16 weight offsets inside d_ws (units: shorts), pre-scaled by INV_*
#define OFF_W0T 0         // [672][128]  (W0s|W0g)^T * INV_M0
#define OFF_W1T 86016     // [192][64]   W1^T * INV_M1
#define OFF_W2T 98304     // [96][32]    W2^T * INV_M2
#define OFF_V0T 101376    // [128][384]  V0^T * INV_H0
#define OFF_V1T 150528    // [64][192]   V1^T * INV_H1
#define OFF_V2T 162816    // [32][96]    V2^T * INV_H2
#define WP_TOTAL 165888

__device__ __forceinline__ short f2bf_rne(float f) {        // prep only
    union { float f; unsigned u; } v; v.f = f;
    unsigned r = v.u + 0x7FFFu + ((v.u >> 16) & 1u);
    return (short)(r >> 16);
}
// 1-VALU bf16 convert (RNE) for the hot kernel
__device__ __forceinline__ short f2bf_fast(float f) {
    unsigned r;
    asm("v_cvt_pk_bf16_f32 %0, %1, %1" : "=v"(r) : "v"(f));
    return (short)r;
}
__device__ __forceinline__ float bf2f(short s) {
    union { unsigned u; float f; } v; v.u = ((unsigned)(unsigned short)s) << 16;
    return v.f;
}

__global__ void prep_weights(const float* __restrict__ W0s, const float* __restrict__ W0g,
                             const float* __restrict__ W1,  const float* __restrict__ W2,
                             const float* __restrict__ V0,  const float* __restrict__ V1,
                             const float* __restrict__ V2,  short* __restrict__ ws)
{
    int i = blockIdx.x * 256 + threadIdx.x;
    if (i < 86016) {                    // W0T [672][128]
        int j = i >> 7, k = i & 127;
        float v = (j < 384) ? W0s[k * 384 + j] : W0g[k * 288 + (j - 384)];
        ws[i] = f2bf_rne(v * INV_M0f);
    } else if (i < 98304) {             // W1T [192][64]
        int e = i - 86016; int w = e >> 6, u = e & 63;
        ws[i] = f2bf_rne(W1[u * 192 + w] * INV_M1f);
    } else if (i < 101376) {            // W2T [96][32]
        int e = i - 98304; int w = e >> 5, u = e & 31;
        ws[i] = f2bf_rne(W2[u * 96 + w] * INV_M2f);
    } else if (i < 150528) {            // V0T [128][384]
        int e = i - 101376; int j = e / 384, w = e % 384;
        ws[i] = f2bf_rne(V0[w * 128 + j] * INV_H0f);
    } else if (i < 162816) {            // V1T [64][192]
        int e = i - 150528; int j = e / 192, w = e % 192;
        ws[i] = f2bf_rne(V1[w * 64 + j] * INV_H1f);
    } else if (i < WP_TOTAL) {          // V2T [32][96]
        int e = i - 162816; int j = e / 96, w = e % 96;
        ws[i] = f2bf_rne(V2[w * 32 + j] * INV_H2f);
    }
}

// ---- LDS layout (shorts), total 35584 shorts = 71168 B ----
// Phase A : x0s [0,4352)=[32][136], sbuf [4352,16896)=[32][392], gbuf top
// Phase D : sbuf read
// B1      : x1T [0,6912)=96x72 rows=(mm*32+node), ubuf1 [6912,26112)=96x200
// B2      : x2T [0,6400)=160x40, ubuf2 [6400,23040)=160x104
// gbuf    : [26112,35584)=[32][296], live Phase A -> end
#define X0_STRIDE 136
#define SB_OFF 4352
#define SB_STRIDE 392
#define GB_OFF 26112
#define GB_STRIDE 296
#define UB1_OFF 6912
#define UB1_STRIDE 200
#define UB2_OFF 6400
#define UB2_STRIDE 104
#define LDS_SHORTS 35584

#define MFMA(a, b, c) __builtin_amdgcn_mfma_f32_16x16x32_bf16((a), (b), (c), 0, 0, 0)

__global__ __launch_bounds__(512, 4) void ffn_main(
    const float* __restrict__ X, const float* __restrict__ Y,
    const float* __restrict__ bs, const float* __restrict__ bg, const float* __restrict__ bo,
    const short* __restrict__ WP, float* __restrict__ out)
{
    __shared__ short lds[LDS_SHORTS];
    short* x0s   = lds;
    short* sbuf  = lds + SB_OFF;
    short* gbuf  = lds + GB_OFF;
    short* x1T   = lds;            // 96 x 72 row-major, row = mm*32+node
    short* x2T   = lds;            // 160 x 40 row-major
    short* ubuf1 = lds + UB1_OFF;  // 96 x 200
    short* ubuf2 = lds + UB2_OFF;  // 160 x 104

    const int tid  = threadIdx.x;
    const int wid  = tid >> 6;     // wave 0..7
    const int lane = tid & 63;
    const int m    = lane & 15;    // A-row / B-col / D-col index
    const int bq   = lane >> 4;    // k-block; D row-group
    const int n0   = blockIdx.x * 32;

    // ---- prefetch first Phase-A weight tile (overlaps x0 staging) ----
    short8 w0c[4];
    float bias_c;
    {
        const short* w = WP + OFF_W0T + (wid * 16 + m) * 128 + bq * 8;
        #pragma unroll
        for (int k = 0; k < 4; ++k) w0c[k] = *(const short8*)(w + k * 32);
        bias_c = bs[wid * 16 + m];          // first jt = wid < 24 -> always bs
    }

    // ---- stage x0 (32 nodes x 128 cols) -> LDS bf16, coalesced ----
    {
        const int node = tid >> 4, c16 = tid & 15;
        const float* xp = X + (size_t)(n0 + node) * 480 + c16 * 8;
        float4 f0 = *(const float4*)xp;
        float4 f1 = *(const float4*)(xp + 4);
        short8 a;
        a[0]=f2bf_fast(f0.x); a[1]=f2bf_fast(f0.y); a[2]=f2bf_fast(f0.z); a[3]=f2bf_fast(f0.w);
        a[4]=f2bf_fast(f1.x); a[5]=f2bf_fast(f1.y); a[6]=f2bf_fast(f1.z); a[7]=f2bf_fast(f1.w);
        *(short8*)(x0s + node * X0_STRIDE + c16 * 8) = a;
    }

    // y for the 8 rows this lane touches: rows t*16 + bq*4 + r
    float yv[2][4];
    #pragma unroll
    for (int t = 0; t < 2; ++t)
        #pragma unroll
        for (int r = 0; r < 4; ++r)
            yv[t][r] = Y[n0 + t * 16 + bq * 4 + r];

    __syncthreads();                                        // [b1]

    // x0 A-fragments, both row-tiles
    short8 a0[2][4];
    #pragma unroll
    for (int t = 0; t < 2; ++t)
        #pragma unroll
        for (int k = 0; k < 4; ++k)
            a0[t][k] = *(const short8*)(x0s + (t * 16 + m) * X0_STRIDE + k * 32 + bq * 8);

    // ---- Phase A: pre(32x672) = x0 @ W0T^T ; s -> sbuf, g -> gbuf ----
    #pragma unroll 1
    for (int i = 0; i < 6; ++i) {
        const int jt = wid + i * 8;
        if (jt >= 42) break;
        const int jn = jt + 8;
        short8 w0n[4];
        float bias_n = 0.f;
        if (jn < 42) {
            const short* w = WP + OFF_W0T + (jn * 16 + m) * 128 + bq * 8;
            #pragma unroll
            for (int k = 0; k < 4; ++k) w0n[k] = *(const short8*)(w + k * 32);
            bias_n = (jn < 24) ? bs[jn * 16 + m] : bg[(jn - 24) * 16 + m];
        }
        f32x4 acc0 = {0.f,0.f,0.f,0.f}, acc1 = {0.f,0.f,0.f,0.f};
        #pragma unroll
        for (int k = 0; k < 4; ++k) {
            acc0 = MFMA(a0[0][k], w0c[k], acc0);
            acc1 = MFMA(a0[1][k], w0c[k], acc1);
        }
        if (jt < 24) {          // silu -> sbuf
            #pragma unroll
            for (int t = 0; t < 2; ++t) {
                f32x4 acc = t ? acc1 : acc0;
                #pragma unroll
                for (int r = 0; r < 4; ++r) {
                    float val = fmaf(acc[r], yv[t][r], bias_c);
                    float e   = __expf(-val);
                    float sv  = val * __builtin_amdgcn_rcpf(1.f + e);
                    sbuf[(t * 16 + bq * 4 + r) * SB_STRIDE + jt * 16 + m] = f2bf_fast(sv);
                }
            }
        } else {                // sigmoid -> gbuf
            #pragma unroll
            for (int t = 0; t < 2; ++t) {
                f32x4 acc = t ? acc1 : acc0;
                #pragma unroll
                for (int r = 0; r < 4; ++r) {
                    float val = fmaf(acc[r], yv[t][r], bias_c);
                    float e   = __expf(-val);
                    float sg  = __builtin_amdgcn_rcpf(1.f + e);
                    gbuf[(t * 16 + bq * 4 + r) * GB_STRIDE + (jt - 24) * 16 + m] = f2bf_fast(sg);
                }
            }
        }
        #pragma unroll
        for (int k = 0; k < 4; ++k) w0c[k] = w0n[k];
        bias_c = bias_n;
    }

    // ---- prefetch Phase-D weights (V0T) + bias before the barrier ----
    short8 v0f[12];
    {
        const short* v = WP + OFF_V0T + (wid * 16 + m) * 384 + bq * 8;
        #pragma unroll
        for (int k = 0; k < 12; ++k) v0f[k] = *(const short8*)(v + k * 32);
    }
    const float bo_r = bo[wid * 16 + m];
    __syncthreads();                                        // [b2]

    // ---- Phase D: o0(32x128) = s @ V0 ; 1 j-tile per wave, dense stores ----
    {
        f32x4 accD0 = {0.f,0.f,0.f,0.f}, accD1 = {0.f,0.f,0.f,0.f};
        #pragma unroll
        for (int k = 0; k < 12; ++k) {
            short8 sa0 = *(const short8*)(sbuf + m * SB_STRIDE + k * 32 + bq * 8);
            short8 sa1 = *(const short8*)(sbuf + (16 + m) * SB_STRIDE + k * 32 + bq * 8);
            accD0 = MFMA(sa0, v0f[k], accD0);
            accD1 = MFMA(sa1, v0f[k], accD1);
        }
        #pragma unroll
        for (int t = 0; t < 2; ++t) {
            f32x4 acc = t ? accD1 : accD0;
            #pragma unroll
            for (int r = 0; r < 4; ++r)
                out[(size_t)(n0 + t * 16 + bq * 4 + r) * 480 + wid * 16 + m] =
                    fmaf(acc[r], yv[t][r], bo_r);
        }
    }

    // ---- prefetch B1-GEMM2 weights: wave -> (ct1 = wid&3, parity p1 = wid>>2)
    const int ct1 = wid & 3, p1 = wid >> 2;
    short8 v1f[6];
    {
        const short* v = WP + OFF_V1T + (ct1 * 16 + m) * 192 + bq * 8;
        #pragma unroll
        for (int k = 0; k < 6; ++k) v1f[k] = *(const short8*)(v + k * 32);
    }
    __syncthreads();   // [b3] sbuf reads done; x1T region may be written

    // ---- stage x1 as 96x72 row-batched matrix: row = mm*32+node ----
    {
        const int node = tid >> 4, c16 = tid & 15;
        const float* xp = X + (size_t)(n0 + node) * 480 + 128 + c16 * 12;
        float4 fa = *(const float4*)xp;
        float4 fb = *(const float4*)(xp + 4);
        float4 fc = *(const float4*)(xp + 8);
        float vals[12] = {fa.x,fa.y,fa.z,fa.w, fb.x,fb.y,fb.z,fb.w, fc.x,fc.y,fc.z,fc.w};
        #pragma unroll
        for (int c = 0; c < 12; ++c) {
            const int u   = c16 * 4 + c / 3;    // static per c
            const int mmv = c % 3;
            x1T[(mmv * 32 + node) * 72 + u] = f2bf_fast(vals[c]);
        }
    }
    __syncthreads();                                        // [b4]

    // ---- B1-GEMM1: C(96x192) = x1T(96x64) @ W1 ; 72 tiles, 9 per wave ----
    {
        f32x4 accs[9];
        #pragma unroll
        for (int ii = 0; ii < 9; ++ii) {
            const unsigned idx = (unsigned)(wid * 9 + ii);
            const int ct = idx / 6u, rt = idx % 6u;
            const short* wb = WP + OFF_W1T + (ct * 16 + m) * 64 + bq * 8;
            short8 b0 = *(const short8*)(wb);
            short8 b1 = *(const short8*)(wb + 32);
            short8 a00 = *(const short8*)(x1T + (rt * 16 + m) * 72 + bq * 8);
            short8 a01 = *(const short8*)(x1T + (rt * 16 + m) * 72 + 32 + bq * 8);
            f32x4 acc = {0.f,0.f,0.f,0.f};
            acc = MFMA(a00, b0, acc);
            acc = MFMA(a01, b1, acc);
            accs[ii] = acc;
        }
        // epilogue: gate + y + cvt -> ubuf1 (all LDS reads above precede writes)
        #pragma unroll
        for (int ii = 0; ii < 9; ++ii) {
            const unsigned idx = (unsigned)(wid * 9 + ii);
            const int ct = idx / 6u, rt = idx % 6u;
            const int w = ct * 16 + m;
            #pragma unroll
            for (int r = 0; r < 4; ++r) {
                const int node = (rt & 1) * 16 + bq * 4 + r;   // row = rt*16+bq*4+r
                float gv = bf2f(gbuf[node * GB_STRIDE + w]);
                ubuf1[(rt * 16 + bq * 4 + r) * UB1_STRIDE + w] =
                    f2bf_fast(accs[ii][r] * yv[rt & 1][r] * gv);
            }
        }
    }
    __syncthreads();                                        // [b5]

    // ---- B1-GEMM2 (o1 = u @ V1, dense stores) + x2T staging (overlapped) ----
    {
        // x2T global loads issued first to hide HBM latency under MFMAs
        const int node2 = tid >> 4, c16 = tid & 15;
        const float* xp2 = X + (size_t)(n0 + node2) * 480 + 320 + c16 * 10;
        float vals[10];
        #pragma unroll
        for (int p = 0; p < 5; ++p) {
            float2 f = *(const float2*)(xp2 + p * 2);
            vals[p * 2] = f.x; vals[p * 2 + 1] = f.y;
        }
        // GEMM2: wave owns (ct1, p1); tiles rt = 2q+p1 -> mm=q, nodes p1*16..+15
        f32x4 o1f[3];
        #pragma unroll
        for (int q = 0; q < 3; ++q) {
            const int rt = q * 2 + p1;
            f32x4 acc = {0.f,0.f,0.f,0.f};
            #pragma unroll
            for (int k = 0; k < 6; ++k) {
                short8 a = *(const short8*)(ubuf1 + (rt * 16 + m) * UB1_STRIDE + k * 32 + bq * 8);
                acc = MFMA(a, v1f[k], acc);
            }
            o1f[q] = acc;
        }
        // dense o1 stores: 12 B contiguous per (node)
        #pragma unroll
        for (int r = 0; r < 4; ++r) {
            const float yy = yv[p1][r];
            float* pp = out + (size_t)(n0 + p1 * 16 + bq * 4 + r) * 480 + 128 + (ct1 * 16 + m) * 3;
            pp[0] = o1f[0][r] * yy; pp[1] = o1f[1][r] * yy; pp[2] = o1f[2][r] * yy;
        }
        // x2T ds_writes: 160x40 row-batched, row = mm*32+node
        #pragma unroll
        for (int c = 0; c < 10; ++c) {
            const int u   = c16 * 2 + c / 5;    // static per c
            const int mmv = c % 5;
            x2T[(mmv * 32 + node2) * 40 + u] = f2bf_fast(vals[c]);
        }
    }

    // ---- prefetch B2-GEMM2 weights (waves 0..3): (ct2 = wid&1, p2 = wid>>1)
    short8 v2f[3];
    if (wid < 4) {
        const short* v = WP + OFF_V2T + ((wid & 1) * 16 + m) * 96 + bq * 8;
        #pragma unroll
        for (int k = 0; k < 3; ++k) v2f[k] = *(const short8*)(v + k * 32);
    }
    __syncthreads();   // [b6] x2T ready; ubuf1 reads done (ubuf2 overlaps it)

    // ---- B2-GEMM1: C(160x96) = x2T(160x32) @ W2 ; 60 tiles, 7-8 per wave ----
    {
        const int ntile = (wid < 4) ? 8 : 7;
        const int base  = (wid < 4) ? wid * 8 : 32 + (wid - 4) * 7;
        f32x4 accs[8];
        #pragma unroll
        for (int ii = 0; ii < 8; ++ii) {
            if (ii < ntile) {
                const unsigned idx = (unsigned)(base + ii);
                const int rt = idx / 6u, ct = idx % 6u;   // rt-major: A-frag reuse
                short8 b = *(const short8*)(WP + OFF_W2T + (ct * 16 + m) * 32 + bq * 8);
                short8 a = *(const short8*)(x2T + (rt * 16 + m) * 40 + bq * 8);
                f32x4 z = {0.f,0.f,0.f,0.f};
                accs[ii] = MFMA(a, b, z);
            }
        }
        #pragma unroll
        for (int ii = 0; ii < 8; ++ii) {
            if (ii < ntile) {
                const unsigned idx = (unsigned)(base + ii);
                const int rt = idx / 6u, ct = idx % 6u;
                const int w = ct * 16 + m;
                #pragma unroll
                for (int r = 0; r < 4; ++r) {
                    const int node = (rt & 1) * 16 + bq * 4 + r;
                    float gv = bf2f(gbuf[node * GB_STRIDE + 192 + w]);
                    ubuf2[(rt * 16 + bq * 4 + r) * UB2_STRIDE + w] =
                        f2bf_fast(accs[ii][r] * yv[rt & 1][r] * gv);
                }
            }
        }
    }
    __syncthreads();                                        // [b7]

    // ---- B2-GEMM2: o2(160x32) = u2 @ V2 (K=96); waves 0..3, dense stores ----
    if (wid < 4) {
        const int ct2 = wid & 1, p2 = wid >> 1;
        f32x4 o2f[5];
        #pragma unroll
        for (int q = 0; q < 5; ++q) {
            const int rt = q * 2 + p2;        // mm = q, nodes p2*16..+15
            f32x4 acc = {0.f,0.f,0.f,0.f};
            #pragma unroll
            for (int k = 0; k < 3; ++k) {
                short8 a = *(const short8*)(ubuf2 + (rt * 16 + m) * UB2_STRIDE + k * 32 + bq * 8);
                acc = MFMA(a, v2f[k], acc);
            }
            o2f[q] = acc;
        }
        #pragma unroll
        for (int r = 0; r < 4; ++r) {
            const float yy = yv[p2][r];
            float* pp = out + (size_t)(n0 + p2 * 16 + bq * 4 + r) * 480 + 320 + (ct2 * 16 + m) * 5;
            pp[0] = o2f[0][r] * yy; pp[1] = o2f[1][r] * yy; pp[2] = o2f[2][r] * yy;
            pp[3] = o2f[3][r] * yy; pp[4] = o2f[4][r] * yy;
        }
    }
}

extern "C" void kernel_launch(void* const* d_in, const int* in_sizes, int n_in,
                              void* d_out, int out_size, void* d_ws, size_t ws_size,
                              hipStream_t stream)
{
    const float* X   = (const float*)d_in[0];
    const float* Y   = (const float*)d_in[1];
    const float* W0s = (const float*)d_in[2];
    const float* bs  = (const float*)d_in[3];
    const float* W0g = (const float*)d_in[4];
    const float* bg  = (const float*)d_in[5];
    const float* W1  = (const float*)d_in[6];
    const float* W2  = (const float*)d_in[7];
    const float* V0  = (const float*)d_in[8];
    const float* bo  = (const float*)d_in[9];
    const float* V1  = (const float*)d_in[10];
    const float* V2  = (const float*)d_in[11];
    short* WP  = (short*)d_ws;           // 331776 B of bf16-packed weights
    float* out = (float*)d_out;

    const int n = in_sizes[0] / 480;     // 200000
    const int tiles = n / 32;            // 6250 32-node tiles (exact)

    prep_weights<<<dim3((WP_TOTAL + 255) / 256), dim3(256), 0, stream>>>(
        W0s, W0g, W1, W2, V0, V1, V2, WP);
    ffn_main<<<dim3(tiles), dim3(512), 0, stream>>>(X, Y, bs, bg, bo, WP, out);
}